// Round 9
// baseline (243.007 us; speedup 1.0000x reference)
//
#include <hip/hip_runtime.h>
#include <hip/hip_bf16.h>
#include <stddef.h>

#define HEADS 12
#define DM 768
#define DK 64
#define SEQ 2048
#define NB 2
#define WSZ (DM * DM)                  // 589824
#define QSCALE 0.18033688011112043f    // log2(e)/8, folded into Q projection

typedef __attribute__((ext_vector_type(8))) short short8;
typedef __attribute__((ext_vector_type(4))) float f32x4;
typedef __attribute__((ext_vector_type(16))) float f32x16;

#define MFMA16(A, B, C) __builtin_amdgcn_mfma_f32_16x16x32_bf16((A), (B), (C), 0, 0, 0)
#define MFMA32(A, B, C) __builtin_amdgcn_mfma_f32_32x32x16_bf16((A), (B), (C), 0, 0, 0)

__device__ __forceinline__ unsigned short f2bf(float x) {
  union { float f; unsigned u; } c;
  c.f = x;
  unsigned r = (c.u + 0x7FFFu + ((c.u >> 16) & 1u)) >> 16;
  return (unsigned short)r;
}
__device__ __forceinline__ float bf2f(unsigned short h) {
  union { float f; unsigned u; } c;
  c.u = ((unsigned)h) << 16;
  return c.f;
}

// async 16B/lane global -> LDS. NOTE: global address is PER-LANE (must
// include the lane term); LDS dest is wave-uniform base, HW adds lane*16.
__device__ __forceinline__ void async16(const void* g, void* l) {
  __builtin_amdgcn_global_load_lds(
      (const __attribute__((address_space(1))) void*)g,
      (__attribute__((address_space(3))) void*)l, 16, 0, 0);
}

// split 2 fp32 -> packed bf16-hi dword + bf16-lo dword (RNE both)
__device__ __forceinline__ void splitpk(float a, float b, unsigned& hu, unsigned& lu) {
  union { __hip_bfloat162 v; unsigned u; } c;
  c.v = __float22bfloat162_rn(make_float2(a, b));
  hu = c.u;
  const float ra = a - bf2f((unsigned short)(hu & 0xFFFFu));
  const float rb = b - bf2f((unsigned short)(hu >> 16));
  c.v = __float22bfloat162_rn(make_float2(ra, rb));
  lu = c.u;
}
__device__ __forceinline__ unsigned pk2bf(float a, float b) {
  union { __hip_bfloat162 v; unsigned u; } c;
  c.v = __float22bfloat162_rn(make_float2(a, b));
  return c.u;
}

// v_permlane32_swap_b32: a.hi31 <-> b.lo31. After: a = {a.lo, b.lo_old},
// b = {a.hi_old, b.hi}. Both outputs usable (one swap fills two words).
__device__ __forceinline__ void pl32swap(unsigned& a, unsigned& b) {
  auto r = __builtin_amdgcn_permlane32_swap(a, b, false, false);
  a = r[0];
  b = r[1];
}

// ===========================================================================
// Fragment-tile layouts (all 512 shorts = 1024 B, one async16 wave-call,
// frag read = tile_base + lane*16):
//  - 16x32 GEMM tile (prep/proj/out): c = (k%32)/8*16 + row%16, e = k%8.
//  - K attn tile [32t x 16d] (A-frag 32x32x16): c = t + (d/8)*32, e = d%8.
//  - V attn tile [16t x 32d] (B-frag 32x32x16): c = d + (t/8)*32, e = t%8.
// ===========================================================================

// ---------------------------------------------------------------------------
// prep: fp32 -> tiled bf16. X (q,k,v): hi only; W (Wk,Wo): hi+lo.
// Block = 64 rows x 128 k, LDS row-major transpose, tiled copy-out.
// ---------------------------------------------------------------------------
__global__ __launch_bounds__(256) void prep_split(
    const float* __restrict__ q, const float* __restrict__ k,
    const float* __restrict__ v, const float* __restrict__ Wk,
    const float* __restrict__ Wo, unsigned short* __restrict__ xq,
    unsigned short* __restrict__ xk, unsigned short* __restrict__ xv,
    unsigned short* __restrict__ wkh, unsigned short* __restrict__ wkl,
    unsigned short* __restrict__ woh, unsigned short* __restrict__ wol) {
  __shared__ __align__(16) unsigned short Lh[64 * 136];
  __shared__ __align__(16) unsigned short Ll[64 * 136];
  const int tid = threadIdx.x;
  int id = blockIdx.x;
  const float* S;
  unsigned short *H, *L = nullptr;
  int RT, RT16;
  if (id < 1152) {
    S = (id < 384) ? q : (id < 768) ? k : v;
    H = (id < 384) ? xq : (id < 768) ? xk : xv;
    id = id % 384; RT = 64; RT16 = 256;
  } else if (id < 1224) {
    S = Wk; H = wkh; L = wkl; id -= 1152; RT = 12; RT16 = 48;
  } else {
    S = Wo; H = woh; L = wol; id -= 1224; RT = 12; RT16 = 48;
  }
  const int rb = id % RT, kb = id / RT;
  const int mlane = tid >> 4;          // row within 16
  const int klane = (tid & 15) * 8;    // k within 128

  // phase 1: coalesced fp32 read -> split -> LDS row-major (pad 136)
#pragma unroll
  for (int rr = 0; rr < 4; ++rr) {
    const int m = rr * 16 + mlane;
    const float* src = &S[(size_t)(rb * 64 + m) * DM + kb * 128 + klane];
    float a[8];
    *(float4*)&a[0] = *(const float4*)&src[0];
    *(float4*)&a[4] = *(const float4*)&src[4];
    if (L) {
      unsigned hu[4], lu[4];
#pragma unroll
      for (int u = 0; u < 4; ++u) splitpk(a[2 * u], a[2 * u + 1], hu[u], lu[u]);
      *(uint4*)&Lh[m * 136 + klane] = *(uint4*)&hu[0];
      *(uint4*)&Ll[m * 136 + klane] = *(uint4*)&lu[0];
    } else {
      unsigned hu[4];
#pragma unroll
      for (int u = 0; u < 4; ++u) hu[u] = pk2bf(a[2 * u], a[2 * u + 1]);
      *(uint4*)&Lh[m * 136 + klane] = *(uint4*)&hu[0];
    }
  }
  __syncthreads();

  // phase 2: copy out in fragment-tile order (16 tiles of [16m x 32k])
  const int t = tid >> 4;              // tile 0..15
  const int ktp = t >> 2, mtp = t & 3;
  const size_t gt = ((size_t)(kb * 4 + ktp) * RT16 + (rb * 4 + mtp)) * 512;
#pragma unroll
  for (int i = 0; i < 4; ++i) {        // kq = i, row = tid&15
    const int c = i * 16 + (tid & 15);
    const int lsrc = (mtp * 16 + (tid & 15)) * 136 + ktp * 32 + i * 8;
    *(uint4*)&H[gt + c * 8] = *(uint4*)&Lh[lsrc];
    if (L) *(uint4*)&L[gt + c * 8] = *(uint4*)&Ll[lsrc];
  }
}

// ---------------------------------------------------------------------------
// PROJ: Y = X @ Wk^T + bk, bf16x2 (Ah*Bh + Ah*Bl). Tile 128x96, grid
// (256,1,3) flat: m = id&31 (XCD-local A sharing), n = id>>5.
// BK=64 -> 12 iterations. LDS 40 KB -> 3 blocks/CU.
// z=0: q hi+lo row-major [B,H,S,DK], pre-scaled by QSCALE.
// z=1: K attn-tiled [bh][t32][d16][512] for 32x32x16 A-frags.
// z=2: V attn-tiled [bh][t16][d32][512] for 32x32x16 B-frags.
// ---------------------------------------------------------------------------
__global__ __launch_bounds__(256, 3) void gemm_proj(
    const unsigned short* __restrict__ Xq, const unsigned short* __restrict__ Xk,
    const unsigned short* __restrict__ Xv, const unsigned short* __restrict__ Bh_,
    const unsigned short* __restrict__ Bl_, const float* __restrict__ bias,
    unsigned short* __restrict__ q_h, unsigned short* __restrict__ q_l,
    unsigned short* __restrict__ k_h, unsigned short* __restrict__ vt_h) {
  __shared__ __align__(16) unsigned short Ash[16 * 512];  // [ks2][mt8]
  __shared__ __align__(16) unsigned short Bsh[12 * 512];  // [ks2][nt6]
  __shared__ __align__(16) unsigned short Bsl[12 * 512];

  const int tid = threadIdx.x, z = blockIdx.z;
  const unsigned short* __restrict__ A = (z == 0) ? Xq : (z == 1) ? Xk : Xv;
  const int id = blockIdx.x;
  const int mt0 = (id & 31) * 8, nt0 = (id >> 5) * 6;  // tile indices
  const int lane = tid & 63, wv = tid >> 6;
  const int l15 = lane & 15, quad = lane >> 4;
  const int wm = (wv >> 1) * 4, wn = (wv & 1) * 3;     // wave tile offsets
  const int lx = lane * 8;                             // shorts

  f32x4 acc[4][3];
#pragma unroll
  for (int i = 0; i < 4; ++i)
#pragma unroll
    for (int j = 0; j < 3; ++j) acc[i][j] = (f32x4){0.f, 0.f, 0.f, 0.f};

  for (int kk = 0; kk < 12; ++kk) {
    const int k2 = kk * 2;
    __syncthreads();
    // A: 16 tiles, 4 per wave
    async16(&A[((size_t)k2 * 256 + mt0 + wv) * 512 + lx], &Ash[wv * 512]);
    async16(&A[((size_t)k2 * 256 + mt0 + wv + 4) * 512 + lx],
            &Ash[(wv + 4) * 512]);
    async16(&A[((size_t)(k2 + 1) * 256 + mt0 + wv) * 512 + lx],
            &Ash[(8 + wv) * 512]);
    async16(&A[((size_t)(k2 + 1) * 256 + mt0 + wv + 4) * 512 + lx],
            &Ash[(12 + wv) * 512]);
    // B: 12 Bh + 12 Bl, 3+3 per wave; slot t = ks*6+nt
#pragma unroll
    for (int i = 0; i < 3; ++i) {
      const int t = wv + 4 * i;
      const int ks = t / 6, nt = t % 6;
      async16(&Bh_[((size_t)(k2 + ks) * 48 + nt0 + nt) * 512 + lx],
              &Bsh[t * 512]);
      async16(&Bl_[((size_t)(k2 + ks) * 48 + nt0 + nt) * 512 + lx],
              &Bsl[t * 512]);
    }
    __syncthreads();

#pragma unroll
    for (int ks = 0; ks < 2; ++ks) {
      short8 bh8[3], bl8[3];
#pragma unroll
      for (int nt = 0; nt < 3; ++nt) {
        bh8[nt] = *(const short8*)&Bsh[(ks * 6 + wn + nt) * 512 + lx];
        bl8[nt] = *(const short8*)&Bsl[(ks * 6 + wn + nt) * 512 + lx];
      }
#pragma unroll
      for (int mt = 0; mt < 4; ++mt) {
        const short8 ah8 = *(const short8*)&Ash[(ks * 8 + wm + mt) * 512 + lx];
#pragma unroll
        for (int nt = 0; nt < 3; ++nt) {
          acc[mt][nt] = MFMA16(ah8, bh8[nt], acc[mt][nt]);
          acc[mt][nt] = MFMA16(ah8, bl8[nt], acc[mt][nt]);
        }
      }
    }
  }

#pragma unroll
  for (int mt = 0; mt < 4; ++mt)
#pragma unroll
    for (int nt = 0; nt < 3; ++nt) {
      const int n = (nt0 + wn + nt) * 16 + l15;
      const float bv = bias[n];
      const int hh = n >> 6, dk = n & 63;
#pragma unroll
      for (int j = 0; j < 4; ++j) {
        const int m = (mt0 + wm + mt) * 16 + quad * 4 + j;  // C/D row=quad*4+reg
        const int b = m >> 11, t = m & 2047;
        const int bh = b * HEADS + hh;
        if (z == 0) {
          const float y = (acc[mt][nt][j] + bv) * QSCALE;
          const unsigned short yh = f2bf(y);
          const int a = (bh * SEQ + t) * DK + dk;
          q_h[a] = yh;
          q_l[a] = f2bf(y - bf2f(yh));
        } else if (z == 1) {
          // K: [bh][t32][d16][512], tile idx = t'*8 + (d'/8)*256 + d'%8
          const int a = bh * 131072 + (t >> 5) * 2048 + (dk >> 4) * 512 +
                        ((t & 31) + ((dk & 15) >> 3) * 32) * 8 + (dk & 7);
          k_h[a] = f2bf(acc[mt][nt][j] + bv);
        } else {
          // V: [bh][t16][d32][512], tile idx = d'*8 + (t'/8)*256 + t'%8
          const int a = bh * 131072 + (t >> 4) * 1024 + (dk >> 5) * 512 +
                        ((dk & 31) + ((t & 15) >> 3) * 32) * 8 + (t & 7);
          vt_h[a] = f2bf(acc[mt][nt][j] + bv);
        }
      }
    }
}

// ---------------------------------------------------------------------------
// OUT: out = cc @ Wo^T + bo (fp32). Tile 64x96, grid 512 flat (m = id&63).
// cc and Wo both pre-tiled; bf16x3. BK=64 -> 12 iterations. LDS 40 KB.
// ---------------------------------------------------------------------------
__global__ __launch_bounds__(256, 2) void gemm_out(
    const unsigned short* __restrict__ Ah_, const unsigned short* __restrict__ Al_,
    const unsigned short* __restrict__ Bh_, const unsigned short* __restrict__ Bl_,
    const float* __restrict__ bias, float* __restrict__ outF) {
  __shared__ __align__(16) unsigned short Ash[8 * 512];   // [ks2][mt4]
  __shared__ __align__(16) unsigned short Asl[8 * 512];
  __shared__ __align__(16) unsigned short Bsh[12 * 512];  // [ks2][nt6]
  __shared__ __align__(16) unsigned short Bsl[12 * 512];

  const int tid = threadIdx.x, id = blockIdx.x;
  const int mt0 = (id & 63) * 4, nt0 = (id >> 6) * 6;
  const int lane = tid & 63, wv = tid >> 6;
  const int l15 = lane & 15, quad = lane >> 4;
  const int wm = (wv >> 1) * 2, wn = (wv & 1) * 3;
  const int lx = lane * 8;

  f32x4 acc[2][3];
#pragma unroll
  for (int i = 0; i < 2; ++i)
#pragma unroll
    for (int j = 0; j < 3; ++j) acc[i][j] = (f32x4){0.f, 0.f, 0.f, 0.f};

  for (int kk = 0; kk < 12; ++kk) {
    const int k2 = kk * 2;
    __syncthreads();
    // A: 8 Ah + 8 Al tiles, 2+2 per wave (wv indexes the 4 m-tiles)
#pragma unroll
    for (int ks = 0; ks < 2; ++ks) {
      async16(&Ah_[((size_t)(k2 + ks) * 256 + mt0 + wv) * 512 + lx],
              &Ash[(ks * 4 + wv) * 512]);
      async16(&Al_[((size_t)(k2 + ks) * 256 + mt0 + wv) * 512 + lx],
              &Asl[(ks * 4 + wv) * 512]);
    }
    // B: 12 Bh + 12 Bl, 3+3 per wave; slot t = ks*6+nt
#pragma unroll
    for (int i = 0; i < 3; ++i) {
      const int t = wv + 4 * i;
      const int ks = t / 6, nt = t % 6;
      async16(&Bh_[((size_t)(k2 + ks) * 48 + nt0 + nt) * 512 + lx],
              &Bsh[t * 512]);
      async16(&Bl_[((size_t)(k2 + ks) * 48 + nt0 + nt) * 512 + lx],
              &Bsl[t * 512]);
    }
    __syncthreads();

#pragma unroll
    for (int ks = 0; ks < 2; ++ks) {
      short8 bh8[3], bl8[3];
#pragma unroll
      for (int nt = 0; nt < 3; ++nt) {
        bh8[nt] = *(const short8*)&Bsh[(ks * 6 + wn + nt) * 512 + lx];
        bl8[nt] = *(const short8*)&Bsl[(ks * 6 + wn + nt) * 512 + lx];
      }
#pragma unroll
      for (int mt = 0; mt < 2; ++mt) {
        const short8 ah8 = *(const short8*)&Ash[(ks * 4 + wm + mt) * 512 + lx];
        const short8 al8 = *(const short8*)&Asl[(ks * 4 + wm + mt) * 512 + lx];
#pragma unroll
        for (int nt = 0; nt < 3; ++nt) {
          acc[mt][nt] = MFMA16(ah8, bh8[nt], acc[mt][nt]);
          acc[mt][nt] = MFMA16(al8, bh8[nt], acc[mt][nt]);
          acc[mt][nt] = MFMA16(ah8, bl8[nt], acc[mt][nt]);
        }
      }
    }
  }

#pragma unroll
  for (int mt = 0; mt < 2; ++mt)
#pragma unroll
    for (int nt = 0; nt < 3; ++nt) {
      const int n = (nt0 + wn + nt) * 16 + l15;
      const float bv = bias[n];
#pragma unroll
      for (int j = 0; j < 4; ++j) {
        const int m = (mt0 + wm + mt) * 16 + quad * 4 + j;
        outF[(size_t)m * DM + n] = acc[mt][nt][j] + bv;
      }
    }
}

// ---------------------------------------------------------------------------
// Flash attention, 32x32x16 MFMA, in-register P. R9: 8-WAVE blocks
// (512 thr), t split 4-ways: waves (qh 2) x (th 4), each wave owns ONE
// 32q x 32t S-tile per iteration (8 QK MFMA + 4 PV MFMA — half the R6
// chain). Same QBLK=64/TBLK=128/grid 768 -> staging traffic UNCHANGED
// (avoids R4's 2x-traffic failure); waves/CU 12 -> 16-24 (VGPR-dependent,
// not forced — R3 lesson). LDS 49.2 KB (stage 32K  U  osh 48K aliased +
// Lred 1K) -> 3 blocks/CU by LDS. Epilogue: 4-way O/l combine (3 osh
// slabs + Lred[8]). Q pre-scaled by log2(e)/8 -> p = exp2(s), no clamp.
// Output written in cc-tiled layout for gemm_out. bh = id%24.
// ---------------------------------------------------------------------------
__global__ __launch_bounds__(512, 4) void attn_mfma(
    const unsigned short* __restrict__ q_h, const unsigned short* __restrict__ q_l,
    const unsigned short* __restrict__ k_h, const unsigned short* __restrict__ vt_h,
    unsigned short* __restrict__ cch, unsigned short* __restrict__ ccl) {
  __shared__ __align__(16) union {
    unsigned short stage[32 * 512];  // K 16 tiles [tt4][dt4] | V 16 [tt8][dt2]
    float osh[3 * 64 * 64];          // epilogue O-combine slabs (aliased)
  } sm;
  __shared__ float Lred[8][32];

  const int tid = threadIdx.x, lane = tid & 63, wv = tid >> 6;
  const int l31 = lane & 31, hi = lane >> 5;
  const int qh = wv & 1, th = wv >> 1;  // qh 0..1 (32q), th 0..3 (32t slice)
  const int id = blockIdx.x;
  const int bh = id % 24, q0 = (id / 24) << 6;
  const int lx = lane * 8;

  // Q B-frags (col=q=lane&31, k=d=ks*16+hi*8+e), hi+lo, direct from global.
  short8 Qf[4][2];
#pragma unroll
  for (int ks = 0; ks < 4; ++ks) {
    const int off = (bh * SEQ + q0 + qh * 32 + l31) * DK + ks * 16 + hi * 8;
    Qf[ks][0] = *(const short8*)&q_h[off];
    Qf[ks][1] = *(const short8*)&q_l[off];
  }

  f32x16 O[2];
#pragma unroll
  for (int i = 0; i < 2; ++i)
#pragma unroll
    for (int r = 0; r < 16; ++r) O[i][r] = 0.f;
  float lsum = 0.f;

  const unsigned short* __restrict__ kbh = k_h + (size_t)bh * 131072;
  const unsigned short* __restrict__ vbh = vt_h + (size_t)bh * 131072;
  unsigned short* const Ks = &sm.stage[0];
  unsigned short* const Vs = &sm.stage[16 * 512];

  for (int t0 = 0; t0 < SEQ; t0 += 128) {
    __syncthreads();  // prev tile reads complete
    if (wv < 4) {
      // K: wave wv stages t32-tile wv, all 4 d16-tiles.
#pragma unroll
      for (int dt = 0; dt < 4; ++dt)
        async16(&kbh[((size_t)(t0 >> 5) + wv) * 2048 + dt * 512 + lx],
                &Ks[(wv * 4 + dt) * 512]);
    } else {
      // V: wave wv-4 stages t16-tiles {2(wv-4), 2(wv-4)+1}, both d32-tiles.
      const int w2 = wv - 4;
#pragma unroll
      for (int i = 0; i < 2; ++i)
#pragma unroll
        for (int dt = 0; dt < 2; ++dt)
          async16(
              &vbh[((size_t)(t0 >> 4) + w2 * 2 + i) * 1024 + dt * 512 + lx],
              &Vs[((w2 * 2 + i) * 2 + dt) * 512]);
    }
    __syncthreads();  // drains vmcnt: tiles visible

    // QK^T: this wave's single 32x32 S-tile (t-slice th), 4 d-chunks.
    f32x16 St;
#pragma unroll
    for (int r = 0; r < 16; ++r) St[r] = 0.f;
    __builtin_amdgcn_s_setprio(1);
#pragma unroll
    for (int ks = 0; ks < 4; ++ks) {
      const short8 kh8 = *(const short8*)&Ks[(th * 4 + ks) * 512 + lx];
      St = MFMA32(kh8, Qf[ks][0], St);
      St = MFMA32(kh8, Qf[ks][1], St);
    }
    __builtin_amdgcn_s_setprio(0);

    // p = exp2(s) in place (no clamp: |s| <~ 9); lsum lane-local.
    {
      float s = 0.f;
#pragma unroll
      for (int r = 0; r < 16; ++r) {
        St[r] = __builtin_amdgcn_exp2f(St[r]);
        s += St[r];
      }
      lsum += s;
    }

    // In-register P -> A-frag: per 16-k chunk pack + 2 permlane32_swap.
    short8 pa[2];
#pragma unroll
    for (int c = 0; c < 2; ++c) {
      unsigned a0 = pk2bf(St[c * 8 + 0], St[c * 8 + 1]);
      unsigned a1 = pk2bf(St[c * 8 + 2], St[c * 8 + 3]);
      unsigned b0 = pk2bf(St[c * 8 + 4], St[c * 8 + 5]);
      unsigned b1 = pk2bf(St[c * 8 + 6], St[c * 8 + 7]);
      pl32swap(a0, b0);
      pl32swap(a1, b1);
      unsigned w[4] = {a0, a1, b0, b1};
      pa[c] = *(short8*)&w[0];
    }

    // O += P V: this wave's 2 t16-chunks x 2 d32-tiles.
    __builtin_amdgcn_s_setprio(1);
#pragma unroll
    for (int tc = 0; tc < 2; ++tc) {
#pragma unroll
      for (int dt = 0; dt < 2; ++dt) {
        const short8 vb8 =
            *(const short8*)&Vs[((th * 2 + tc) * 2 + dt) * 512 + lx];
        O[dt] = MFMA32(pa[tc], vb8, O[dt]);
      }
    }
    __builtin_amdgcn_s_setprio(0);
  }

  // --- epilogue: combine 4 t-slices, write cc-tiled ---
  {
    float l = lsum + __shfl_xor(lsum, 32);
    if (lane < 32) Lred[wv][lane] = l;
  }
  asm volatile("s_waitcnt vmcnt(0)" ::: "memory");
  __syncthreads();
  if (th > 0) {  // waves 2..7 write their O slab (th-1)
    float* slab = &sm.osh[(th - 1) * 4096];
#pragma unroll
    for (int dt = 0; dt < 2; ++dt)
#pragma unroll
      for (int r = 0; r < 16; ++r) {
        const int qloc = (r & 3) + 8 * (r >> 2) + 4 * hi;
        slab[(qh * 32 + qloc) * 64 + dt * 32 + l31] = O[dt][r];
      }
  }
  __syncthreads();
  if (th == 0) {  // waves 0,1 combine and write
    const int b = bh / HEADS, hh = bh % HEADS;
#pragma unroll
    for (int dt = 0; dt < 2; ++dt)
#pragma unroll
      for (int r = 0; r < 16; ++r) {
        const int qloc = (r & 3) + 8 * (r >> 2) + 4 * hi;
        const float inv = 1.0f / (Lred[qh][qloc] + Lred[qh + 2][qloc] +
                                  Lred[qh + 4][qloc] + Lred[qh + 6][qloc]);
        const int oidx = (qh * 32 + qloc) * 64 + dt * 32 + l31;
        const float y = (O[dt][r] + sm.osh[oidx] + sm.osh[4096 + oidx] +
                         sm.osh[8192 + oidx]) *
                        inv;
        const int m = b * SEQ + q0 + qh * 32 + qloc;  // cc row
        const int kk = hh * 64 + dt * 32 + l31;
        const int a = ((kk >> 5) * 256 + (m >> 4)) * 512 +
                      (((kk & 31) >> 3) * 16 + (m & 15)) * 8 + (kk & 7);
        const unsigned short yh = f2bf(y);
        cch[a] = yh;
        ccl[a] = f2bf(y - bf2f(yh));
      }
  }
}

extern "C" void kernel_launch(void* const* d_in, const int* in_sizes, int n_in,
                              void* d_out, int out_size, void* d_ws,
                              size_t ws_size, hipStream_t stream) {
  const float* q = (const float*)d_in[0];
  const float* k = (const float*)d_in[1];
  const float* v = (const float*)d_in[2];
  const float* Wk = (const float*)d_in[3];
  const float* bk = (const float*)d_in[4];
  const float* Wo = (const float*)d_in[5];
  const float* bo = (const float*)d_in[6];
  float* out = (float*)d_out;

  const size_t SZ = (size_t)NB * SEQ * DM;  // 3,145,728
  unsigned short* ws16 = (unsigned short*)d_ws;
  // [0,3SZ): x tiled splits (dead after proj); cc aliases [0,2SZ) after attn.
  unsigned short* xq = ws16;
  unsigned short* xk = ws16 + SZ;
  unsigned short* xv = ws16 + 2 * SZ;
  unsigned short* cch = xq;
  unsigned short* ccl = xk;
  // [3SZ,7SZ): projections (dead after attn).
  unsigned short* qp_h = ws16 + 3 * SZ;
  unsigned short* qp_l = ws16 + 4 * SZ;
  unsigned short* kp = ws16 + 5 * SZ;
  unsigned short* vtp = ws16 + 6 * SZ;
  // [7SZ, 7SZ+4WSZ): W tiled splits (wk live to proj, wo live to out).
  unsigned short* wkh = ws16 + 7 * SZ;
  unsigned short* wkl = wkh + WSZ;
  unsigned short* woh = wkl + WSZ;
  unsigned short* wol = woh + WSZ;
  // footprint: 7*SZ + 4*WSZ shorts = 48.8 MB

  // 1) prep: tiled bf16 splits of q/k/v (hi) and Wk/Wo (hi+lo)
  prep_split<<<dim3(1296), 256, 0, stream>>>(q, k, v, Wk, Wo, xq, xk, xv, wkh,
                                             wkl, woh, wol);
  // 2) q/k/v all projected with Wk/bk (faithful source bug); K/V attn-tiled
  gemm_proj<<<dim3(256, 1, 3), 256, 0, stream>>>(xq, xk, xv, wkh, wkl, bk,
                                                 qp_h, qp_l, kp, vtp);
  // 3) flash attention -> cc-tiled split bf16 (overwrites xq/xk)
  attn_mfma<<<dim3(768), 512, 0, stream>>>(qp_h, qp_l, kp, vtp, cch, ccl);
  // 4) out = cc @ Wo^T + bo (fp32)
  gemm_out<<<dim3(512), 256, 0, stream>>>(cch, ccl, woh, wol, bo, out);
}

// Round 10
// 181.757 us; speedup vs baseline: 1.3370x; 1.3370x over previous
//
#include <hip/hip_runtime.h>
#include <hip/hip_bf16.h>
#include <stddef.h>

#define HEADS 12
#define DM 768
#define DK 64
#define SEQ 2048
#define NB 2
#define WSZ (DM * DM)                  // 589824
#define QSCALE 0.18033688011112043f    // log2(e)/8, folded into Q projection

typedef __attribute__((ext_vector_type(8))) short short8;
typedef __attribute__((ext_vector_type(4))) float f32x4;
typedef __attribute__((ext_vector_type(16))) float f32x16;

#define MFMA16(A, B, C) __builtin_amdgcn_mfma_f32_16x16x32_bf16((A), (B), (C), 0, 0, 0)
#define MFMA32(A, B, C) __builtin_amdgcn_mfma_f32_32x32x16_bf16((A), (B), (C), 0, 0, 0)

__device__ __forceinline__ unsigned short f2bf(float x) {
  union { float f; unsigned u; } c;
  c.f = x;
  unsigned r = (c.u + 0x7FFFu + ((c.u >> 16) & 1u)) >> 16;
  return (unsigned short)r;
}
__device__ __forceinline__ float bf2f(unsigned short h) {
  union { float f; unsigned u; } c;
  c.u = ((unsigned)h) << 16;
  return c.f;
}

// async 16B/lane global -> LDS. NOTE: global address is PER-LANE (must
// include the lane term); LDS dest is wave-uniform base, HW adds lane*16.
__device__ __forceinline__ void async16(const void* g, void* l) {
  __builtin_amdgcn_global_load_lds(
      (const __attribute__((address_space(1))) void*)g,
      (__attribute__((address_space(3))) void*)l, 16, 0, 0);
}

// split 2 fp32 -> packed bf16-hi dword + bf16-lo dword (RNE both)
__device__ __forceinline__ void splitpk(float a, float b, unsigned& hu, unsigned& lu) {
  union { __hip_bfloat162 v; unsigned u; } c;
  c.v = __float22bfloat162_rn(make_float2(a, b));
  hu = c.u;
  const float ra = a - bf2f((unsigned short)(hu & 0xFFFFu));
  const float rb = b - bf2f((unsigned short)(hu >> 16));
  c.v = __float22bfloat162_rn(make_float2(ra, rb));
  lu = c.u;
}
__device__ __forceinline__ unsigned pk2bf(float a, float b) {
  union { __hip_bfloat162 v; unsigned u; } c;
  c.v = __float22bfloat162_rn(make_float2(a, b));
  return c.u;
}

// v_permlane32_swap_b32: a.hi31 <-> b.lo31. After: a = {a.lo, b.lo_old},
// b = {a.hi_old, b.hi}. Both outputs usable (one swap fills two words).
__device__ __forceinline__ void pl32swap(unsigned& a, unsigned& b) {
  auto r = __builtin_amdgcn_permlane32_swap(a, b, false, false);
  a = r[0];
  b = r[1];
}

// ===========================================================================
// Fragment-tile layouts (all 512 shorts = 1024 B, one async16 wave-call,
// frag read = tile_base + lane*16):
//  - 16x32 GEMM tile (prep/proj/out): c = (k%32)/8*16 + row%16, e = k%8.
//  - K attn tile [32t x 16d] (A-frag 32x32x16): c = t + (d/8)*32, e = d%8.
//  - V attn tile [16t x 32d] (B-frag 32x32x16): c = d + (t/8)*32, e = t%8.
// ===========================================================================

// ---------------------------------------------------------------------------
// prep: fp32 -> tiled bf16. X (q,k,v): hi only; W (Wk,Wo): hi+lo.
// Block = 64 rows x 128 k, LDS row-major transpose, tiled copy-out.
// ---------------------------------------------------------------------------
__global__ __launch_bounds__(256) void prep_split(
    const float* __restrict__ q, const float* __restrict__ k,
    const float* __restrict__ v, const float* __restrict__ Wk,
    const float* __restrict__ Wo, unsigned short* __restrict__ xq,
    unsigned short* __restrict__ xk, unsigned short* __restrict__ xv,
    unsigned short* __restrict__ wkh, unsigned short* __restrict__ wkl,
    unsigned short* __restrict__ woh, unsigned short* __restrict__ wol) {
  __shared__ __align__(16) unsigned short Lh[64 * 136];
  __shared__ __align__(16) unsigned short Ll[64 * 136];
  const int tid = threadIdx.x;
  int id = blockIdx.x;
  const float* S;
  unsigned short *H, *L = nullptr;
  int RT, RT16;
  if (id < 1152) {
    S = (id < 384) ? q : (id < 768) ? k : v;
    H = (id < 384) ? xq : (id < 768) ? xk : xv;
    id = id % 384; RT = 64; RT16 = 256;
  } else if (id < 1224) {
    S = Wk; H = wkh; L = wkl; id -= 1152; RT = 12; RT16 = 48;
  } else {
    S = Wo; H = woh; L = wol; id -= 1224; RT = 12; RT16 = 48;
  }
  const int rb = id % RT, kb = id / RT;
  const int mlane = tid >> 4;          // row within 16
  const int klane = (tid & 15) * 8;    // k within 128

  // phase 1: coalesced fp32 read -> split -> LDS row-major (pad 136)
#pragma unroll
  for (int rr = 0; rr < 4; ++rr) {
    const int m = rr * 16 + mlane;
    const float* src = &S[(size_t)(rb * 64 + m) * DM + kb * 128 + klane];
    float a[8];
    *(float4*)&a[0] = *(const float4*)&src[0];
    *(float4*)&a[4] = *(const float4*)&src[4];
    if (L) {
      unsigned hu[4], lu[4];
#pragma unroll
      for (int u = 0; u < 4; ++u) splitpk(a[2 * u], a[2 * u + 1], hu[u], lu[u]);
      *(uint4*)&Lh[m * 136 + klane] = *(uint4*)&hu[0];
      *(uint4*)&Ll[m * 136 + klane] = *(uint4*)&lu[0];
    } else {
      unsigned hu[4];
#pragma unroll
      for (int u = 0; u < 4; ++u) hu[u] = pk2bf(a[2 * u], a[2 * u + 1]);
      *(uint4*)&Lh[m * 136 + klane] = *(uint4*)&hu[0];
    }
  }
  __syncthreads();

  // phase 2: copy out in fragment-tile order (16 tiles of [16m x 32k])
  const int t = tid >> 4;              // tile 0..15
  const int ktp = t >> 2, mtp = t & 3;
  const size_t gt = ((size_t)(kb * 4 + ktp) * RT16 + (rb * 4 + mtp)) * 512;
#pragma unroll
  for (int i = 0; i < 4; ++i) {        // kq = i, row = tid&15
    const int c = i * 16 + (tid & 15);
    const int lsrc = (mtp * 16 + (tid & 15)) * 136 + ktp * 32 + i * 8;
    *(uint4*)&H[gt + c * 8] = *(uint4*)&Lh[lsrc];
    if (L) *(uint4*)&L[gt + c * 8] = *(uint4*)&Ll[lsrc];
  }
}

// ---------------------------------------------------------------------------
// PROJ: Y = X @ Wk^T + bk, bf16x2 (Ah*Bh + Ah*Bl). Tile 128x96, grid
// (256,1,3) flat: m = id&31 (XCD-local A sharing), n = id>>5.
// BK=64 -> 12 iterations. LDS 40 KB -> 3 blocks/CU.
// z=0: q hi ONLY row-major [B,H,S,DK], pre-scaled by QSCALE (R10: q_l
// dropped — attn QK uses single-bf16 Q, matching K's precision).
// z=1: K attn-tiled [bh][t32][d16][512] for 32x32x16 A-frags.
// z=2: V attn-tiled [bh][t16][d32][512] for 32x32x16 B-frags.
// ---------------------------------------------------------------------------
__global__ __launch_bounds__(256, 3) void gemm_proj(
    const unsigned short* __restrict__ Xq, const unsigned short* __restrict__ Xk,
    const unsigned short* __restrict__ Xv, const unsigned short* __restrict__ Bh_,
    const unsigned short* __restrict__ Bl_, const float* __restrict__ bias,
    unsigned short* __restrict__ q_h, unsigned short* __restrict__ q_l,
    unsigned short* __restrict__ k_h, unsigned short* __restrict__ vt_h) {
  __shared__ __align__(16) unsigned short Ash[16 * 512];  // [ks2][mt8]
  __shared__ __align__(16) unsigned short Bsh[12 * 512];  // [ks2][nt6]
  __shared__ __align__(16) unsigned short Bsl[12 * 512];

  const int tid = threadIdx.x, z = blockIdx.z;
  const unsigned short* __restrict__ A = (z == 0) ? Xq : (z == 1) ? Xk : Xv;
  const int id = blockIdx.x;
  const int mt0 = (id & 31) * 8, nt0 = (id >> 5) * 6;  // tile indices
  const int lane = tid & 63, wv = tid >> 6;
  const int l15 = lane & 15, quad = lane >> 4;
  const int wm = (wv >> 1) * 4, wn = (wv & 1) * 3;     // wave tile offsets
  const int lx = lane * 8;                             // shorts

  f32x4 acc[4][3];
#pragma unroll
  for (int i = 0; i < 4; ++i)
#pragma unroll
    for (int j = 0; j < 3; ++j) acc[i][j] = (f32x4){0.f, 0.f, 0.f, 0.f};

  for (int kk = 0; kk < 12; ++kk) {
    const int k2 = kk * 2;
    __syncthreads();
    // A: 16 tiles, 4 per wave
    async16(&A[((size_t)k2 * 256 + mt0 + wv) * 512 + lx], &Ash[wv * 512]);
    async16(&A[((size_t)k2 * 256 + mt0 + wv + 4) * 512 + lx],
            &Ash[(wv + 4) * 512]);
    async16(&A[((size_t)(k2 + 1) * 256 + mt0 + wv) * 512 + lx],
            &Ash[(8 + wv) * 512]);
    async16(&A[((size_t)(k2 + 1) * 256 + mt0 + wv + 4) * 512 + lx],
            &Ash[(12 + wv) * 512]);
    // B: 12 Bh + 12 Bl, 3+3 per wave; slot t = ks*6+nt
#pragma unroll
    for (int i = 0; i < 3; ++i) {
      const int t = wv + 4 * i;
      const int ks = t / 6, nt = t % 6;
      async16(&Bh_[((size_t)(k2 + ks) * 48 + nt0 + nt) * 512 + lx],
              &Bsh[t * 512]);
      async16(&Bl_[((size_t)(k2 + ks) * 48 + nt0 + nt) * 512 + lx],
              &Bsl[t * 512]);
    }
    __syncthreads();

#pragma unroll
    for (int ks = 0; ks < 2; ++ks) {
      short8 bh8[3], bl8[3];
#pragma unroll
      for (int nt = 0; nt < 3; ++nt) {
        bh8[nt] = *(const short8*)&Bsh[(ks * 6 + wn + nt) * 512 + lx];
        bl8[nt] = *(const short8*)&Bsl[(ks * 6 + wn + nt) * 512 + lx];
      }
#pragma unroll
      for (int mt = 0; mt < 4; ++mt) {
        const short8 ah8 = *(const short8*)&Ash[(ks * 8 + wm + mt) * 512 + lx];
#pragma unroll
        for (int nt = 0; nt < 3; ++nt) {
          acc[mt][nt] = MFMA16(ah8, bh8[nt], acc[mt][nt]);
          acc[mt][nt] = MFMA16(ah8, bl8[nt], acc[mt][nt]);
        }
      }
    }
  }

#pragma unroll
  for (int mt = 0; mt < 4; ++mt)
#pragma unroll
    for (int nt = 0; nt < 3; ++nt) {
      const int n = (nt0 + wn + nt) * 16 + l15;
      const float bv = bias[n];
      const int hh = n >> 6, dk = n & 63;
#pragma unroll
      for (int j = 0; j < 4; ++j) {
        const int m = (mt0 + wm + mt) * 16 + quad * 4 + j;  // C/D row=quad*4+reg
        const int b = m >> 11, t = m & 2047;
        const int bh = b * HEADS + hh;
        if (z == 0) {
          const float y = (acc[mt][nt][j] + bv) * QSCALE;
          const int a = (bh * SEQ + t) * DK + dk;
          q_h[a] = f2bf(y);  // hi only (R10)
        } else if (z == 1) {
          // K: [bh][t32][d16][512], tile idx = t'*8 + (d'/8)*256 + d'%8
          const int a = bh * 131072 + (t >> 5) * 2048 + (dk >> 4) * 512 +
                        ((t & 31) + ((dk & 15) >> 3) * 32) * 8 + (dk & 7);
          k_h[a] = f2bf(acc[mt][nt][j] + bv);
        } else {
          // V: [bh][t16][d32][512], tile idx = d'*8 + (t'/8)*256 + t'%8
          const int a = bh * 131072 + (t >> 4) * 1024 + (dk >> 5) * 512 +
                        ((dk & 31) + ((t & 15) >> 3) * 32) * 8 + (t & 7);
          vt_h[a] = f2bf(acc[mt][nt][j] + bv);
        }
      }
    }
}

// ---------------------------------------------------------------------------
// OUT: out = cc @ Wo^T + bo (fp32). Tile 64x96, grid 512 flat (m = id&63).
// cc and Wo both pre-tiled; bf16x3. BK=64 -> 12 iterations. LDS 40 KB.
// ---------------------------------------------------------------------------
__global__ __launch_bounds__(256, 2) void gemm_out(
    const unsigned short* __restrict__ Ah_, const unsigned short* __restrict__ Al_,
    const unsigned short* __restrict__ Bh_, const unsigned short* __restrict__ Bl_,
    const float* __restrict__ bias, float* __restrict__ outF) {
  __shared__ __align__(16) unsigned short Ash[8 * 512];   // [ks2][mt4]
  __shared__ __align__(16) unsigned short Asl[8 * 512];
  __shared__ __align__(16) unsigned short Bsh[12 * 512];  // [ks2][nt6]
  __shared__ __align__(16) unsigned short Bsl[12 * 512];

  const int tid = threadIdx.x, id = blockIdx.x;
  const int mt0 = (id & 63) * 4, nt0 = (id >> 6) * 6;
  const int lane = tid & 63, wv = tid >> 6;
  const int l15 = lane & 15, quad = lane >> 4;
  const int wm = (wv >> 1) * 2, wn = (wv & 1) * 3;
  const int lx = lane * 8;

  f32x4 acc[2][3];
#pragma unroll
  for (int i = 0; i < 2; ++i)
#pragma unroll
    for (int j = 0; j < 3; ++j) acc[i][j] = (f32x4){0.f, 0.f, 0.f, 0.f};

  for (int kk = 0; kk < 12; ++kk) {
    const int k2 = kk * 2;
    __syncthreads();
    // A: 8 Ah + 8 Al tiles, 2+2 per wave (wv indexes the 4 m-tiles)
#pragma unroll
    for (int ks = 0; ks < 2; ++ks) {
      async16(&Ah_[((size_t)(k2 + ks) * 256 + mt0 + wv) * 512 + lx],
              &Ash[(ks * 4 + wv) * 512]);
      async16(&Al_[((size_t)(k2 + ks) * 256 + mt0 + wv) * 512 + lx],
              &Asl[(ks * 4 + wv) * 512]);
    }
    // B: 12 Bh + 12 Bl, 3+3 per wave; slot t = ks*6+nt
#pragma unroll
    for (int i = 0; i < 3; ++i) {
      const int t = wv + 4 * i;
      const int ks = t / 6, nt = t % 6;
      async16(&Bh_[((size_t)(k2 + ks) * 48 + nt0 + nt) * 512 + lx],
              &Bsh[t * 512]);
      async16(&Bl_[((size_t)(k2 + ks) * 48 + nt0 + nt) * 512 + lx],
              &Bsl[t * 512]);
    }
    __syncthreads();

#pragma unroll
    for (int ks = 0; ks < 2; ++ks) {
      short8 bh8[3], bl8[3];
#pragma unroll
      for (int nt = 0; nt < 3; ++nt) {
        bh8[nt] = *(const short8*)&Bsh[(ks * 6 + wn + nt) * 512 + lx];
        bl8[nt] = *(const short8*)&Bsl[(ks * 6 + wn + nt) * 512 + lx];
      }
#pragma unroll
      for (int mt = 0; mt < 2; ++mt) {
        const short8 ah8 = *(const short8*)&Ash[(ks * 4 + wm + mt) * 512 + lx];
        const short8 al8 = *(const short8*)&Asl[(ks * 4 + wm + mt) * 512 + lx];
#pragma unroll
        for (int nt = 0; nt < 3; ++nt) {
          acc[mt][nt] = MFMA16(ah8, bh8[nt], acc[mt][nt]);
          acc[mt][nt] = MFMA16(al8, bh8[nt], acc[mt][nt]);
          acc[mt][nt] = MFMA16(ah8, bl8[nt], acc[mt][nt]);
        }
      }
    }
  }

#pragma unroll
  for (int mt = 0; mt < 2; ++mt)
#pragma unroll
    for (int nt = 0; nt < 3; ++nt) {
      const int n = (nt0 + wn + nt) * 16 + l15;
      const float bv = bias[n];
#pragma unroll
      for (int j = 0; j < 4; ++j) {
        const int m = (mt0 + wm + mt) * 16 + quad * 4 + j;
        outF[(size_t)m * DM + n] = acc[mt][nt][j] + bv;
      }
    }
}

// ---------------------------------------------------------------------------
// Flash attention, 32x32x16 MFMA, in-register P. R6 structure (proven best
// 55.0 us) with R10 change: Q is single-bf16 (hi only) in QK^T — K and V
// are already single-bf16, so Q hi+lo precision was asymmetric overkill
// (absmax was invariant across the R5->R6 P-path restructure, indicating
// V/cc quantization dominates error, not Q). QK MFMAs 16 -> 8 per
// wave-iter (total 24 -> 16, -33% matrix work), Qf -8 VGPR.
// 4-wave blocks (qh, th) own 32q x 64t; TBLK=128, 16 iters; single-buffer
// staging, 2 barriers/iter; P redistributed in-register via cvt_pk +
// permlane32_swap. LDS 33 KB (K 16K + V 16K; epilogue osh aliases stage).
// NO occupancy forcing (R3/R9: spills). Q pre-scaled by log2(e)/8.
// Output written in cc-tiled layout for gemm_out. Grid 768, bh = id%24.
// ---------------------------------------------------------------------------
__global__ __launch_bounds__(256, 3) void attn_mfma(
    const unsigned short* __restrict__ q_h, const unsigned short* __restrict__ q_l,
    const unsigned short* __restrict__ k_h, const unsigned short* __restrict__ vt_h,
    unsigned short* __restrict__ cch, unsigned short* __restrict__ ccl) {
  __shared__ __align__(16) union {
    unsigned short stage[32 * 512];  // K 16 tiles [tt4][dt4] | V 16 [tt8][dt2]
    float osh[64 * 64];              // epilogue O-combine (loop-dead alias)
  } sm;
  __shared__ float Lred[4][32];

  const int tid = threadIdx.x, lane = tid & 63, wv = tid >> 6;
  const int l31 = lane & 31, hi = lane >> 5;
  const int qh = wv & 1, th = wv >> 1;
  const int id = blockIdx.x;
  const int bh = id % 24, q0 = (id / 24) << 6;
  const int lx = lane * 8;

  // Q B-frags (col=q=lane&31, k=d=ks*16+hi*8+e), hi ONLY, direct from global.
  short8 Qf[4];
#pragma unroll
  for (int ks = 0; ks < 4; ++ks) {
    const int off = (bh * SEQ + q0 + qh * 32 + l31) * DK + ks * 16 + hi * 8;
    Qf[ks] = *(const short8*)&q_h[off];
  }

  f32x16 O[2];
#pragma unroll
  for (int i = 0; i < 2; ++i)
#pragma unroll
    for (int r = 0; r < 16; ++r) O[i][r] = 0.f;
  float lsum = 0.f;

  const unsigned short* __restrict__ kbh = k_h + (size_t)bh * 131072;
  const unsigned short* __restrict__ vbh = vt_h + (size_t)bh * 131072;
  unsigned short* const Ks = &sm.stage[0];
  unsigned short* const Vs = &sm.stage[16 * 512];

  for (int t0 = 0; t0 < SEQ; t0 += 128) {
    __syncthreads();  // prev tile reads complete
    // K: wave wv stages t32-tile wv, all 4 d16-tiles.
#pragma unroll
    for (int dt = 0; dt < 4; ++dt)
      async16(&kbh[((size_t)(t0 >> 5) + wv) * 2048 + dt * 512 + lx],
              &Ks[(wv * 4 + dt) * 512]);
    // V: wave wv stages t16-tiles {2wv, 2wv+1}, both d32-tiles.
#pragma unroll
    for (int i = 0; i < 2; ++i)
#pragma unroll
      for (int dt = 0; dt < 2; ++dt)
        async16(&vbh[((size_t)(t0 >> 4) + wv * 2 + i) * 1024 + dt * 512 + lx],
                &Vs[((wv * 2 + i) * 2 + dt) * 512]);
    __syncthreads();  // drains vmcnt: tiles visible

    // QK^T: S^T quadrants, 2 t32-tiles (wave's 64-t half) x 4 d-chunks.
    f32x16 St[2];
#pragma unroll
    for (int i = 0; i < 2; ++i)
#pragma unroll
      for (int r = 0; r < 16; ++r) St[i][r] = 0.f;
    __builtin_amdgcn_s_setprio(1);
#pragma unroll
    for (int tt = 0; tt < 2; ++tt)
#pragma unroll
      for (int ks = 0; ks < 4; ++ks) {
        const short8 kh8 =
            *(const short8*)&Ks[((th * 2 + tt) * 4 + ks) * 512 + lx];
        St[tt] = MFMA32(kh8, Qf[ks], St[tt]);
      }
    __builtin_amdgcn_s_setprio(0);

    // p = exp2(s) in place (no clamp: |s| <~ 9); lsum is lane-local (all 32
    // values share q = lane&31).
#pragma unroll
    for (int tt = 0; tt < 2; ++tt) {
      float s = 0.f;
#pragma unroll
      for (int r = 0; r < 16; ++r) {
        St[tt][r] = __builtin_amdgcn_exp2f(St[tt][r]);
        s += St[tt][r];
      }
      lsum += s;
    }

    // In-register P -> A-frag: per 16-k chunk pack + 2 permlane32_swap.
    short8 pa[4];
#pragma unroll
    for (int tt = 0; tt < 2; ++tt)
#pragma unroll
      for (int c = 0; c < 2; ++c) {
        unsigned a0 = pk2bf(St[tt][c * 8 + 0], St[tt][c * 8 + 1]);
        unsigned a1 = pk2bf(St[tt][c * 8 + 2], St[tt][c * 8 + 3]);
        unsigned b0 = pk2bf(St[tt][c * 8 + 4], St[tt][c * 8 + 5]);
        unsigned b1 = pk2bf(St[tt][c * 8 + 6], St[tt][c * 8 + 7]);
        pl32swap(a0, b0);
        pl32swap(a1, b1);
        unsigned w[4] = {a0, a1, b0, b1};
        pa[tt * 2 + c] = *(short8*)&w[0];
      }

    // O += P V: 4 t16-chunks x 2 d32-tiles.
    __builtin_amdgcn_s_setprio(1);
#pragma unroll
    for (int tc = 0; tc < 4; ++tc) {
#pragma unroll
      for (int dt = 0; dt < 2; ++dt) {
        const short8 vb8 =
            *(const short8*)&Vs[((th * 4 + tc) * 2 + dt) * 512 + lx];
        O[dt] = MFMA32(pa[tc], vb8, O[dt]);
      }
    }
    __builtin_amdgcn_s_setprio(0);
  }

  // --- epilogue: combine t-halves, write cc-tiled ---
  {
    float l = lsum + __shfl_xor(lsum, 32);
    if (lane < 32) Lred[wv][lane] = l;
  }
  asm volatile("s_waitcnt vmcnt(0)" ::: "memory");
  __syncthreads();
  if (th == 1) {
#pragma unroll
    for (int dt = 0; dt < 2; ++dt)
#pragma unroll
      for (int r = 0; r < 16; ++r) {
        const int qloc = (r & 3) + 8 * (r >> 2) + 4 * hi;
        sm.osh[(qh * 32 + qloc) * 64 + dt * 32 + l31] = O[dt][r];
      }
  }
  __syncthreads();
  if (th == 0) {
    const int b = bh / HEADS, hh = bh % HEADS;
#pragma unroll
    for (int dt = 0; dt < 2; ++dt)
#pragma unroll
      for (int r = 0; r < 16; ++r) {
        const int qloc = (r & 3) + 8 * (r >> 2) + 4 * hi;
        const float inv = 1.0f / (Lred[qh][qloc] + Lred[qh + 2][qloc]);
        const float y =
            (O[dt][r] + sm.osh[(qh * 32 + qloc) * 64 + dt * 32 + l31]) * inv;
        const int m = b * SEQ + q0 + qh * 32 + qloc;  // cc row
        const int kk = hh * 64 + dt * 32 + l31;
        const int a = ((kk >> 5) * 256 + (m >> 4)) * 512 +
                      (((kk & 31) >> 3) * 16 + (m & 15)) * 8 + (kk & 7);
        const unsigned short yh = f2bf(y);
        cch[a] = yh;
        ccl[a] = f2bf(y - bf2f(yh));
      }
  }
}

extern "C" void kernel_launch(void* const* d_in, const int* in_sizes, int n_in,
                              void* d_out, int out_size, void* d_ws,
                              size_t ws_size, hipStream_t stream) {
  const float* q = (const float*)d_in[0];
  const float* k = (const float*)d_in[1];
  const float* v = (const float*)d_in[2];
  const float* Wk = (const float*)d_in[3];
  const float* bk = (const float*)d_in[4];
  const float* Wo = (const float*)d_in[5];
  const float* bo = (const float*)d_in[6];
  float* out = (float*)d_out;

  const size_t SZ = (size_t)NB * SEQ * DM;  // 3,145,728
  unsigned short* ws16 = (unsigned short*)d_ws;
  // [0,3SZ): x tiled splits (dead after proj); cc aliases [0,2SZ) after attn.
  unsigned short* xq = ws16;
  unsigned short* xk = ws16 + SZ;
  unsigned short* xv = ws16 + 2 * SZ;
  unsigned short* cch = xq;
  unsigned short* ccl = xk;
  // [3SZ,7SZ): projections (dead after attn). q_l unused since R10.
  unsigned short* qp_h = ws16 + 3 * SZ;
  unsigned short* qp_l = ws16 + 4 * SZ;
  unsigned short* kp = ws16 + 5 * SZ;
  unsigned short* vtp = ws16 + 6 * SZ;
  // [7SZ, 7SZ+4WSZ): W tiled splits (wk live to proj, wo live to out).
  unsigned short* wkh = ws16 + 7 * SZ;
  unsigned short* wkl = wkh + WSZ;
  unsigned short* woh = wkl + WSZ;
  unsigned short* wol = woh + WSZ;
  // footprint: 7*SZ + 4*WSZ shorts = 48.8 MB

  // 1) prep: tiled bf16 splits of q/k/v (hi) and Wk/Wo (hi+lo)
  prep_split<<<dim3(1296), 256, 0, stream>>>(q, k, v, Wk, Wo, xq, xk, xv, wkh,
                                             wkl, woh, wol);
  // 2) q/k/v all projected with Wk/bk (faithful source bug); K/V attn-tiled
  gemm_proj<<<dim3(256, 1, 3), 256, 0, stream>>>(xq, xk, xv, wkh, wkl, bk,
                                                 qp_h, qp_l, kp, vtp);
  // 3) flash attention -> cc-tiled split bf16 (overwrites xq/xk)
  attn_mfma<<<dim3(768), 256, 0, stream>>>(qp_h, qp_l, kp, vtp, cch, ccl);
  // 4) out = cc @ Wo^T + bo (fp32)
  gemm_out<<<dim3(512), 256, 0, stream>>>(cch, ccl, woh, wol, bo, out);
}